// Round 1
// baseline (657.796 us; speedup 1.0000x reference)
//
#include <hip/hip_runtime.h>

// LSTM scan: B=8192 independent chains, T=2048 serial steps, D=H=2.
// One thread per batch element; weights in registers; fast sigmoid/tanh
// via v_exp_f32 + v_rcp_f32. float4 x-loads (2 timesteps each) with
// 2-iteration software prefetch.

#define LOG2E 1.4426950408889634f

__device__ __forceinline__ float sigm(float x) {
    // 1 / (1 + 2^(-x*log2e))
    return __builtin_amdgcn_rcpf(1.0f + __builtin_amdgcn_exp2f(-LOG2E * x));
}

__device__ __forceinline__ float tanh_f(float x) {
    // 1 - 2/(1 + 2^(2x*log2e)) ; saturates correctly at +-1 via exp2 overflow->inf
    return 1.0f - 2.0f * __builtin_amdgcn_rcpf(1.0f + __builtin_amdgcn_exp2f((2.0f * LOG2E) * x));
}

__global__ __launch_bounds__(64, 1) void lstm_seq_kernel(
    const float* __restrict__ x,
    const float* __restrict__ h0,
    const float* __restrict__ c0,
    const float* __restrict__ w_ih,
    const float* __restrict__ w_hh,
    const float* __restrict__ b_ih,
    const float* __restrict__ b_hh,
    float* __restrict__ out,
    int B, int T)
{
    const int b = blockIdx.x * blockDim.x + threadIdx.x;
    if (b >= B) return;

    // Hoist weights to registers (uniform across threads; cached loads).
    float wi0[8], wi1[8], wh0[8], wh1[8], bias[8];
#pragma unroll
    for (int g = 0; g < 8; ++g) {
        wi0[g]  = w_ih[2 * g + 0];
        wi1[g]  = w_ih[2 * g + 1];
        wh0[g]  = w_hh[2 * g + 0];
        wh1[g]  = w_hh[2 * g + 1];
        bias[g] = b_ih[g] + b_hh[g];   // fold both biases
    }

    float h_0 = h0[2 * b + 0], h_1 = h0[2 * b + 1];
    float c_0 = c0[2 * b + 0], c_1 = c0[2 * b + 1];

    // x row for this element: T*D = 2T floats = T/2 float4s, contiguous.
    const int NI = T >> 1;  // float4s per row (each = 2 timesteps)
    const float4* __restrict__ xp =
        reinterpret_cast<const float4*>(x) + (size_t)b * NI;

    // gate order rows 0..7 = i0,i1,f0,f1,g0,g1,o0,o1
    auto step = [&](float x0, float x1) {
        float gg[8];
#pragma unroll
        for (int g = 0; g < 8; ++g) {
            gg[g] = fmaf(wh1[g], h_1,
                    fmaf(wh0[g], h_0,
                    fmaf(wi1[g], x1,
                    fmaf(wi0[g], x0, bias[g]))));
        }
        float i0 = sigm(gg[0]), i1 = sigm(gg[1]);
        float f0 = sigm(gg[2]), f1 = sigm(gg[3]);
        float t0 = tanh_f(gg[4]), t1 = tanh_f(gg[5]);
        float o0 = sigm(gg[6]), o1 = sigm(gg[7]);
        c_0 = fmaf(f0, c_0, i0 * t0);
        c_1 = fmaf(f1, c_1, i1 * t1);
        h_0 = o0 * tanh_f(c_0);
        h_1 = o1 * tanh_f(c_1);
    };

    // Software pipeline: prefetch 2 float4s (4 timesteps, ~800 cyc lead).
    float4 xa = xp[0];
    float4 xb = xp[1];
    for (int it = 0; it < NI; ++it) {
        float4 xn = xa;
        if (it + 2 < NI) xn = xp[it + 2];
        step(xa.x, xa.y);
        step(xa.z, xa.w);
        xa = xb;
        xb = xn;
    }

    out[2 * b + 0] = c_0;
    out[2 * b + 1] = c_1;
}

extern "C" void kernel_launch(void* const* d_in, const int* in_sizes, int n_in,
                              void* d_out, int out_size, void* d_ws, size_t ws_size,
                              hipStream_t stream) {
    const float* x    = (const float*)d_in[0];
    const float* h0   = (const float*)d_in[1];
    const float* c0   = (const float*)d_in[2];
    const float* w_ih = (const float*)d_in[3];
    const float* w_hh = (const float*)d_in[4];
    const float* b_ih = (const float*)d_in[5];
    const float* b_hh = (const float*)d_in[6];
    float* out = (float*)d_out;

    const int B = in_sizes[1] / 2;           // h0 is (B, H=2)
    const int T = in_sizes[0] / (B * 2);     // x is (B, T, D=2)

    dim3 block(64);
    dim3 grid((B + 63) / 64);
    hipLaunchKernelGGL(lstm_seq_kernel, grid, block, 0, stream,
                       x, h0, c0, w_ih, w_hh, b_ih, b_hh, out, B, T);
}

// Round 2
// 481.756 us; speedup vs baseline: 1.3654x; 1.3654x over previous
//
#include <hip/hip_runtime.h>

// LSTM scan, B=8192 chains, T=2048 steps, D=H=2.
// 4 lanes per batch element (one quad): slotA = {i0,i1,g0,g1}, slotB =
// {f0,f1,o0,o1} across lanes q0..q3. All cross-lane traffic is DPP
// quad_perm (VALU pipe, no LDS latency):
//   - h broadcast: quad bcast lane0 / lane1
//   - gate exchange: quad_perm [2,3,0,1]
// x-projection (bias + Wih*x) is off the serial chain; only 2 h-FMAs,
// one fused nonlinearity (rcp(1+exp2(a*g))*m+d), one exchange, c-fma,
// tanh(c), h-mul remain per slot per step.

#define LOG2E 1.4426950408889634f

template <int CTRL>
__device__ __forceinline__ float qperm(float v) {
    int i = __builtin_bit_cast(int, v);
    i = __builtin_amdgcn_update_dpp(0, i, CTRL, 0xf, 0xf, true);
    return __builtin_bit_cast(float, i);
}
// quad_perm encodings
#define QP_BCAST0 0x00  // (0,0,0,0)
#define QP_BCAST1 0x55  // (1,1,1,1)
#define QP_SWAP2  0x4E  // (2,3,0,1)

__device__ __forceinline__ float tanh_f(float x) {
    return 1.0f - 2.0f * __builtin_amdgcn_rcpf(1.0f + __builtin_amdgcn_exp2f((2.0f * LOG2E) * x));
}

__global__ __launch_bounds__(64, 1) void lstm_quad_kernel(
    const float* __restrict__ x,
    const float* __restrict__ h0,
    const float* __restrict__ c0,
    const float* __restrict__ w_ih,
    const float* __restrict__ w_hh,
    const float* __restrict__ b_ih,
    const float* __restrict__ b_hh,
    float* __restrict__ out,
    int B, int T)
{
    const int tid = blockIdx.x * blockDim.x + threadIdx.x;
    const int e = tid >> 2;        // batch element
    const int q = tid & 3;         // lane within quad
    if (e >= B) return;

    // Gate rows (weight layout rows 0..7 = i0,i1,f0,f1,g0,g1,o0,o1):
    // slotA: q0->i0(0) q1->i1(1) q2->g0(4) q3->g1(5)
    // slotB: q0->f0(2) q1->f1(3) q2->o0(6) q3->o1(7)
    const int rA = (q < 2) ? q : q + 2;
    const int rB = rA + 2;

    const float wiA0 = w_ih[2 * rA], wiA1 = w_ih[2 * rA + 1];
    const float whA0 = w_hh[2 * rA], whA1 = w_hh[2 * rA + 1];
    const float biasA = b_ih[rA] + b_hh[rA];
    const float wiB0 = w_ih[2 * rB], wiB1 = w_ih[2 * rB + 1];
    const float whB0 = w_hh[2 * rB], whB1 = w_hh[2 * rB + 1];
    const float biasB = b_ih[rB] + b_hh[rB];

    // slotA nonlinearity: sigma for q0,q1 ; tanh for q2,q3.
    // unified: n = m * rcp(1 + exp2(a*g)) + d
    const bool isTanh = (q >= 2);
    const float aA = isTanh ? (2.0f * LOG2E) : (-LOG2E);
    const float mA = isTanh ? -2.0f : 1.0f;
    const float dA = isTanh ? 1.0f : 0.0f;

    // h,c valid in lanes q0 (index 0) and q1 (index 1); q2,q3 carry copies.
    float h = h0[2 * e + (q & 1)];
    float c = c0[2 * e + (q & 1)];

    const int NI = T >> 1;  // float4s per element row (2 timesteps each)
    const float4* __restrict__ xp =
        reinterpret_cast<const float4*>(x) + (size_t)e * NI;

    auto step = [&](float x0, float x1) {
        float hh0 = qperm<QP_BCAST0>(h);
        float hh1 = qperm<QP_BCAST1>(h);
        // x-part: off the h-dependency chain (compiler schedules early)
        float axA = fmaf(wiA1, x1, fmaf(wiA0, x0, biasA));
        float axB = fmaf(wiB1, x1, fmaf(wiB0, x0, biasB));
        float gA = fmaf(whA1, hh1, fmaf(whA0, hh0, axA));
        float gB = fmaf(whB1, hh1, fmaf(whB0, hh0, axB));
        // slotA: sigma(i) in q0/q1, tanh(g) in q2/q3
        float nA = fmaf(mA, __builtin_amdgcn_rcpf(1.0f + __builtin_amdgcn_exp2f(aA * gA)), dA);
        // slotB: sigma for all lanes (f in q0/q1, o in q2/q3)
        float nB = __builtin_amdgcn_rcpf(1.0f + __builtin_amdgcn_exp2f(-LOG2E * gB));
        // bring q2/q3 values (tanh g, sigma o) into q0/q1 (and vice versa)
        float xA = qperm<QP_SWAP2>(nA);  // q0 gets tanh(g0), q1 gets tanh(g1)
        float xB = qperm<QP_SWAP2>(nB);  // q0 gets sigma(o0), q1 gets sigma(o1)
        // valid in q0/q1; q2/q3 compute bounded garbage (never read back)
        c = fmaf(nB, c, nA * xA);
        float tc = tanh_f(c);
        h = xB * tc;
    };

    // 2-deep float4 prefetch (4 timesteps of lead)
    float4 xa = xp[0];
    float4 xb = xp[1];
    for (int it = 0; it < NI; ++it) {
        float4 xn = xa;
        if (it + 2 < NI) xn = xp[it + 2];
        step(xa.x, xa.y);
        step(xa.z, xa.w);
        xa = xb;
        xb = xn;
    }

    if (q < 2) out[2 * e + q] = c;
}

extern "C" void kernel_launch(void* const* d_in, const int* in_sizes, int n_in,
                              void* d_out, int out_size, void* d_ws, size_t ws_size,
                              hipStream_t stream) {
    const float* x    = (const float*)d_in[0];
    const float* h0   = (const float*)d_in[1];
    const float* c0   = (const float*)d_in[2];
    const float* w_ih = (const float*)d_in[3];
    const float* w_hh = (const float*)d_in[4];
    const float* b_ih = (const float*)d_in[5];
    const float* b_hh = (const float*)d_in[6];
    float* out = (float*)d_out;

    const int B = in_sizes[1] / 2;           // h0 is (B, H=2)
    const int T = in_sizes[0] / (B * 2);     // x is (B, T, D=2)

    const int threads = B * 4;               // 4 lanes per element
    dim3 block(64);
    dim3 grid((threads + 63) / 64);
    hipLaunchKernelGGL(lstm_quad_kernel, grid, block, 0, stream,
                       x, h0, c0, w_ih, w_hh, b_ih, b_hh, out, B, T);
}

// Round 3
// 329.445 us; speedup vs baseline: 1.9967x; 1.4623x over previous
//
#include <hip/hip_runtime.h>

// LSTM scan, B=8192 chains, T=2048 steps, D=H=2.
// 4 lanes per batch element (one quad); all cross-lane via DPP quad_perm.
// x streamed through a 2x8-float4 register double-buffer (16 timesteps per
// buffer): refill loads are issued right after a buffer is consumed and fly
// during the other buffer's 16 steps (~1300 cyc > ~900 cyc HBM latency), so
// the per-iteration vmcnt(0) drain of the old 2-deep rotation is gone.

#define LOG2E 1.4426950408889634f

template <int CTRL>
__device__ __forceinline__ float qperm(float v) {
    int i = __builtin_bit_cast(int, v);
    i = __builtin_amdgcn_update_dpp(0, i, CTRL, 0xf, 0xf, true);
    return __builtin_bit_cast(float, i);
}
#define QP_BCAST0 0x00  // (0,0,0,0)
#define QP_BCAST1 0x55  // (1,1,1,1)
#define QP_SWAP2  0x4E  // (2,3,0,1)

__device__ __forceinline__ float tanh_f(float x) {
    return 1.0f - 2.0f * __builtin_amdgcn_rcpf(1.0f + __builtin_amdgcn_exp2f((2.0f * LOG2E) * x));
}

__global__ __launch_bounds__(64, 1) void lstm_quad_db_kernel(
    const float* __restrict__ x,
    const float* __restrict__ h0,
    const float* __restrict__ c0,
    const float* __restrict__ w_ih,
    const float* __restrict__ w_hh,
    const float* __restrict__ b_ih,
    const float* __restrict__ b_hh,
    float* __restrict__ out,
    int B, int T)
{
    const int tid = blockIdx.x * blockDim.x + threadIdx.x;
    const int e = tid >> 2;        // batch element
    const int q = tid & 3;         // lane within quad
    if (e >= B) return;

    // slotA rows: q0->i0(0) q1->i1(1) q2->g0(4) q3->g1(5); slotB = +2
    const int rA = (q < 2) ? q : q + 2;
    const int rB = rA + 2;

    const float wiA0 = w_ih[2 * rA], wiA1 = w_ih[2 * rA + 1];
    const float whA0 = w_hh[2 * rA], whA1 = w_hh[2 * rA + 1];
    const float biasA = b_ih[rA] + b_hh[rA];
    const float wiB0 = w_ih[2 * rB], wiB1 = w_ih[2 * rB + 1];
    const float whB0 = w_hh[2 * rB], whB1 = w_hh[2 * rB + 1];
    const float biasB = b_ih[rB] + b_hh[rB];

    // slotA nonlinearity: sigma (q0,q1) / tanh (q2,q3), unified as
    // n = m * rcp(1 + exp2(a*g)) + d
    const bool isTanh = (q >= 2);
    const float aA = isTanh ? (2.0f * LOG2E) : (-LOG2E);
    const float mA = isTanh ? -2.0f : 1.0f;
    const float dA = isTanh ? 1.0f : 0.0f;

    float h = h0[2 * e + (q & 1)];
    float c = c0[2 * e + (q & 1)];

    const int NI = T >> 1;  // float4s per element row (2 timesteps each)
    const float4* __restrict__ xp =
        reinterpret_cast<const float4*>(x) + (size_t)e * NI;

    auto step = [&](float x0, float x1) {
        float hh0 = qperm<QP_BCAST0>(h);
        float hh1 = qperm<QP_BCAST1>(h);
        float axA = fmaf(wiA1, x1, fmaf(wiA0, x0, biasA));
        float axB = fmaf(wiB1, x1, fmaf(wiB0, x0, biasB));
        float gA = fmaf(whA1, hh1, fmaf(whA0, hh0, axA));
        float gB = fmaf(whB1, hh1, fmaf(whB0, hh0, axB));
        float nA = fmaf(mA, __builtin_amdgcn_rcpf(1.0f + __builtin_amdgcn_exp2f(aA * gA)), dA);
        float nB = __builtin_amdgcn_rcpf(1.0f + __builtin_amdgcn_exp2f(-LOG2E * gB));
        float xA = qperm<QP_SWAP2>(nA);  // q0: tanh(g0), q1: tanh(g1)
        float xB = qperm<QP_SWAP2>(nB);  // q0: sigma(o0), q1: sigma(o1)
        c = fmaf(nB, c, nA * xA);
        float tc = tanh_f(c);
        h = xB * tc;
    };

    constexpr int BV = 8;              // float4s per buffer = 16 timesteps
    float4 A[BV], Bb[BV];

    auto loadbuf = [&](float4* buf, int batch) {
#pragma unroll
        for (int j = 0; j < BV; ++j) buf[j] = xp[batch * BV + j];
    };
    auto consume = [&](const float4* buf) {
#pragma unroll
        for (int j = 0; j < BV; ++j) {
            step(buf[j].x, buf[j].y);
            step(buf[j].z, buf[j].w);
        }
    };

    const int nb = NI / BV;            // full 8-float4 batches
    int bi = 0;
    if (nb >= 2) {
        loadbuf(A, 0);
        loadbuf(Bb, 1);
        for (bi = 0; bi + 1 < nb; bi += 2) {
            consume(A);
            if (bi + 2 < nb) loadbuf(A, bi + 2);
            consume(Bb);
            if (bi + 3 < nb) loadbuf(Bb, bi + 3);
        }
        if (bi < nb) { consume(A); ++bi; }   // odd nb: last batch sits in A
    }
    // scalar tail (empty for T=2048)
    for (int i = bi * BV; i < NI; ++i) {
        float4 v = xp[i];
        step(v.x, v.y);
        step(v.z, v.w);
    }

    if (q < 2) out[2 * e + q] = c;
}

extern "C" void kernel_launch(void* const* d_in, const int* in_sizes, int n_in,
                              void* d_out, int out_size, void* d_ws, size_t ws_size,
                              hipStream_t stream) {
    const float* x    = (const float*)d_in[0];
    const float* h0   = (const float*)d_in[1];
    const float* c0   = (const float*)d_in[2];
    const float* w_ih = (const float*)d_in[3];
    const float* w_hh = (const float*)d_in[4];
    const float* b_ih = (const float*)d_in[5];
    const float* b_hh = (const float*)d_in[6];
    float* out = (float*)d_out;

    const int B = in_sizes[1] / 2;           // h0 is (B, H=2)
    const int T = in_sizes[0] / (B * 2);     // x is (B, T, D=2)

    const int threads = B * 4;               // 4 lanes per element
    dim3 block(64);
    dim3 grid((threads + 63) / 64);
    hipLaunchKernelGGL(lstm_quad_db_kernel, grid, block, 0, stream,
                       x, h0, c0, w_ih, w_hh, b_ih, b_hh, out, B, T);
}